// Round 5
// baseline (123.214 us; speedup 1.0000x reference)
//
#include <hip/hip_runtime.h>
#include <hip/hip_bf16.h>

#define TPB 1024  // 16 waves
#define BM 32
#define NROW 32768
#define NBLK (NROW / BM)
#define VV 1024
#define KD 256
#define TT 2048

#define LP_OFF 2L
#define ZQ_OFF (2L + 33554432L)
#define EM_OFF (33554434L + 8388608L)

// ws layout (floats)
#define WS_HIST 0
#define WS_CSUM 1024
#define WS_SSUM 2048
#define WS_MSUM 3072
#define WS_E8 4096  // repacked bf16 e: 512 KB
#define WS_NEED (4096 * 4 + 32 * 1024 * 8 * 2)

typedef __attribute__((ext_vector_type(8))) short bf16x8;
typedef __attribute__((ext_vector_type(4))) float f32x4;

__device__ __forceinline__ void gl_lds16(const float* g, float* l) {
  __builtin_amdgcn_global_load_lds(
      (const __attribute__((address_space(1))) void*)g,
      (__attribute__((address_space(3))) void*)l, 16, 0, 0);
}

__device__ __forceinline__ unsigned short f2bf(float x) {  // RNE
  unsigned u = __float_as_uint(x);
  unsigned r = ((u >> 16) & 1u) + 0x7FFFu;
  return (unsigned short)((u + r) >> 16);
}

__device__ __forceinline__ unsigned foldf(float v) {  // order-preserving
  unsigned b = __float_as_uint(v);
  return b ^ ((unsigned)((int)b >> 31) | 0x80000000u);
}
__device__ __forceinline__ float unfoldf(unsigned k) {
  unsigned s = (unsigned)((int)k >> 31);
  return __uint_as_float(k ^ (0x80000000u | (~s & 0x7FFFFFFFu)));
}

// B layout: unit(o,n) = [w=n>>6][step=o>>2][nt=(n>>4)&3][g=o&3][lm=n&15]
// -> each wave's K-stream is 32 KB contiguous; each load instr = 1 KB.
__global__ __launch_bounds__(256) void tok_prep(
    const float* __restrict__ cw, unsigned short* __restrict__ e8) {
  int t = blockIdx.x * 256 + threadIdx.x;  // 32768
  int o = t >> 10, n = t & 1023;
  const float* src = cw + (size_t)(1 + n) * KD + (o << 3);
  float4 a = *(const float4*)src;
  float4 b = *(const float4*)(src + 4);
  int4 pk;
  pk.x = f2bf(a.x) | ((unsigned)f2bf(a.y) << 16);
  pk.y = f2bf(a.z) | ((unsigned)f2bf(a.w) << 16);
  pk.z = f2bf(b.x) | ((unsigned)f2bf(b.y) << 16);
  pk.w = f2bf(b.z) | ((unsigned)f2bf(b.w) << 16);
  int U = ((n >> 6) << 11) + ((o >> 2) << 8) + (((n >> 4) & 3) << 6) +
          ((o & 3) << 4) + (n & 15);
  *(int4*)(e8 + ((size_t)U << 3)) = pk;
}

__global__ __launch_bounds__(TPB, 4) void tok_mfma(
    const float* __restrict__ z, const float* __restrict__ mask,
    const float* __restrict__ cw, const unsigned short* __restrict__ e8,
    float* __restrict__ out, float* __restrict__ ws) {
  __shared__ __align__(16) float z_s[BM][260];        // padded: +4 breaks conflicts
  __shared__ __align__(16) unsigned short z8u[8192];  // swizzled oct-planes 16 KB
  __shared__ unsigned wkey[16][2][33];
  __shared__ float wsum_s[16][33];
  __shared__ float Mrow_s[32], lse_s[32];
  __shared__ float exv_s[32][4];
  __shared__ int exi_s[32][4];
  __shared__ int argi[32];
  __shared__ float mask_s[32];
  __shared__ float cred[16], sred[16];

  const int tid = threadIdx.x;
  const int lane = tid & 63;
  const int w = tid >> 6;   // 0..15
  const int g = lane >> 4;  // 0..3
  const int lm = lane & 15;
  const int c0 = w << 6;  // wave's 64-col base
  const int n0 = blockIdx.x * BM;

  // ---- stage z fp32 rows (1 row = 1 KB contiguous per gl_lds16 call) ----
  gl_lds16(&z[(size_t)(n0 + w) * KD + (lane << 2)], &z_s[w][0]);
  gl_lds16(&z[(size_t)(n0 + 16 + w) * KD + (lane << 2)], &z_s[16 + w][0]);
  if (tid < 32) mask_s[tid] = mask[n0 + tid];
  __syncthreads();

  // ---- convert to swizzled bf16 oct-planes (lane-contiguous reads) ----
  {
    int r = tid >> 5, o = tid & 31;
    float4 a = *(const float4*)&z_s[r][o << 3];
    float4 b = *(const float4*)&z_s[r][(o << 3) + 4];
    int4 pk;
    pk.x = f2bf(a.x) | ((unsigned)f2bf(a.y) << 16);
    pk.y = f2bf(a.z) | ((unsigned)f2bf(a.w) << 16);
    pk.z = f2bf(b.x) | ((unsigned)f2bf(b.y) << 16);
    pk.w = f2bf(b.z) | ((unsigned)f2bf(b.w) << 16);
    *(int4*)&z8u[(unsigned)(((o << 5) + (r ^ ((o & 7) << 2))) << 3)] = pk;
  }
  __syncthreads();

  // ---- MFMA main loop: 2-deep B prefetch, zero barriers ----
  const bf16x8* za = (const bf16x8*)z8u;
  const bf16x8* bb = (const bf16x8*)e8 + (w << 11) + (g << 4) + lm;
  f32x4 accA[4], accB[4];
  const f32x4 zz = {0.f, 0.f, 0.f, 0.f};
#pragma unroll
  for (int nt = 0; nt < 4; ++nt) { accA[nt] = zz; accB[nt] = zz; }
  bf16x8 bA[4], bB[4], bC[4];
#pragma unroll
  for (int nt = 0; nt < 4; ++nt) bA[nt] = bb[nt << 6];
#pragma unroll
  for (int nt = 0; nt < 4; ++nt) bB[nt] = bb[256 + (nt << 6)];
#pragma unroll
  for (int step = 0; step < 8; ++step) {
    if (step < 6) {
#pragma unroll
      for (int nt = 0; nt < 4; ++nt) bC[nt] = bb[((step + 2) << 8) + (nt << 6)];
    }
    const int oct = (step << 2) + g;
    const int sw = (oct & 7) << 2;
    bf16x8 a0 = za[(oct << 5) + (lm ^ sw)];
    bf16x8 a1 = za[(oct << 5) + ((16 + lm) ^ sw)];
#pragma unroll
    for (int nt = 0; nt < 4; ++nt) {
      accA[nt] = __builtin_amdgcn_mfma_f32_16x16x32_bf16(a0, bA[nt], accA[nt], 0, 0, 0);
      accB[nt] = __builtin_amdgcn_mfma_f32_16x16x32_bf16(a1, bA[nt], accB[nt], 0, 0, 0);
    }
#pragma unroll
    for (int nt = 0; nt < 4; ++nt) { bA[nt] = bB[nt]; bB[nt] = bC[nt]; }
  }

  // D layout: row = mt*16 + g*4 + j, col = c0 + nt*16 + lm
  unsigned colpack[4];
#pragma unroll
  for (int nt = 0; nt < 4; ++nt)
    colpack[nt] = 1023u - (unsigned)(c0 + (nt << 4) + lm);

  // ---- E1: per-wave top-2 packed keys per row (fused max) ----
  auto phase1 = [&](f32x4(&ac)[4], int mt) {
#pragma unroll
    for (int j = 0; j < 4; ++j) {
      int r = (mt << 4) + (g << 2) + j;
      unsigned cur[4];
#pragma unroll
      for (int nt = 0; nt < 4; ++nt)
        cur[nt] = (foldf(ac[nt][j]) & 0xFFFFFC00u) | colpack[nt];
      unsigned k1 = cur[0];
#pragma unroll
      for (int nt = 1; nt < 4; ++nt) k1 = k1 > cur[nt] ? k1 : cur[nt];
#pragma unroll
      for (int d = 1; d <= 8; d <<= 1) {
        unsigned o2 = __shfl_xor(k1, d);
        k1 = k1 > o2 ? k1 : o2;
      }
#pragma unroll
      for (int nt = 0; nt < 4; ++nt)
        if (cur[nt] == k1) cur[nt] = 0u;
      unsigned k2 = cur[0];
#pragma unroll
      for (int nt = 1; nt < 4; ++nt) k2 = k2 > cur[nt] ? k2 : cur[nt];
#pragma unroll
      for (int d = 1; d <= 8; d <<= 1) {
        unsigned o2 = __shfl_xor(k2, d);
        k2 = k2 > o2 ? k2 : o2;
      }
      if (lm == 0) {
        wkey[w][0][r] = k1;
        wkey[w][1][r] = k2;
      }
    }
  };
  phase1(accA, 0);
  phase1(accB, 1);
  __syncthreads();

  // ---- per-row comp max (once, 32 threads; keys are order-preserving) ----
  if (tid < 32) {
    int r = tid;
    unsigned mk = wkey[0][0][r];
#pragma unroll
    for (int w2 = 1; w2 < 16; ++w2) {
      unsigned k = wkey[w2][0][r];
      mk = mk > k ? mk : k;
    }
    Mrow_s[r] = unfoldf(mk & 0xFFFFFC00u);
  }
  __syncthreads();

  // ---- E2: exp partial sums ----
  auto phase2 = [&](f32x4(&ac)[4], int mt) {
#pragma unroll
    for (int j = 0; j < 4; ++j) {
      int r = (mt << 4) + (g << 2) + j;
      float M = Mrow_s[r];
      float s = 0.f;
#pragma unroll
      for (int nt = 0; nt < 4; ++nt) s += __expf(ac[nt][j] - M);
#pragma unroll
      for (int d = 1; d <= 8; d <<= 1) s += __shfl_xor(s, d);
      if (lm == 0) wsum_s[w][r] = s;
    }
  };
  phase2(accA, 0);
  phase2(accB, 1);
  __syncthreads();

  if (tid < 32) {
    int r = tid;
    float S = 0.f;
#pragma unroll
    for (int w2 = 0; w2 < 16; ++w2) S += wsum_s[w2][r];
    lse_s[r] = Mrow_s[r] + __logf(S);
  }
  __syncthreads();

  // ---- E3: log_probs store ----
  auto phase3 = [&](f32x4(&ac)[4], int mt) {
#pragma unroll
    for (int j = 0; j < 4; ++j) {
      int r = (mt << 4) + (g << 2) + j;
      float lse = lse_s[r];
      size_t base = LP_OFF + (size_t)(n0 + r) * VV;
#pragma unroll
      for (int nt = 0; nt < 4; ++nt)
        out[base + c0 + (nt << 4) + lm] = ac[nt][j] - lse;
    }
  };
  phase3(accA, 0);
  phase3(accB, 1);

  // ---- E4A: global comp top-4 per row (wave w owns rows 2w, 2w+1) ----
#pragma unroll
  for (int rr = 0; rr < 2; ++rr) {
    int row = (w << 1) + rr;
    unsigned key = (lane < 32) ? wkey[lane >> 1][lane & 1][row] : 0u;
#pragma unroll
    for (int t2 = 0; t2 < 4; ++t2) {
      unsigned mk = key;
#pragma unroll
      for (int d = 1; d <= 32; d <<= 1) {
        unsigned o2 = __shfl_xor(mk, d);
        mk = mk > o2 ? mk : o2;
      }
      if (lane == 0) exi_s[row][t2] = (int)(1023u - (mk & 0x3FFu));
      if (key == mk) key = 0u;
    }
  }
  __syncthreads();  // exi visible (E4B uses own wave's rows, but keep ordered)

  // ---- E4B: exact fp32 dots for 4 candidates x 2 rows per wave ----
  {
    int p = lane >> 3;   // 0..7: (row_half, cand)
    int seg = lane & 7;  // 32-float segment
    int row = (w << 1) + (p >> 2);
    int cd = p & 3;
    int cand = exi_s[row][cd];
    const float* er = cw + (size_t)(1 + cand) * KD + (seg << 5);
    const float* zr = &z_s[row][seg << 5];
    float s = 0.f;
#pragma unroll
    for (int i2 = 0; i2 < 8; ++i2) {
      float4 a4 = *(const float4*)(zr + (i2 << 2));
      float4 b4 = *(const float4*)(er + (i2 << 2));
      s += a4.x * b4.x + a4.y * b4.y + a4.z * b4.z + a4.w * b4.w;
    }
    s += __shfl_xor(s, 1);
    s += __shfl_xor(s, 2);
    s += __shfl_xor(s, 4);
    if (seg == 0) exv_s[row][cd] = s;
  }
  __syncthreads();

  // ---- final argmax (exact values, first-index tiebreak) + histogram ----
  if (tid < 32) {
    int row = tid;
    float bv = exv_s[row][0];
    int bi = exi_s[row][0];
#pragma unroll
    for (int c = 1; c < 4; ++c) {
      float v = exv_s[row][c];
      int ci = exi_s[row][c];
      if (v > bv || (v == bv && ci < bi)) { bv = v; bi = ci; }
    }
    argi[row] = bi;
    atomicAdd(&ws[WS_HIST + bi], mask_s[row]);  // mask=1.0 adds: exact
  }
  __syncthreads();

  // ---- E5: z_q gather + commitment + smoothness ----
  float csum = 0.f, ssum = 0.f;
  const bool has_prev = (n0 % TT) != 0;
#pragma unroll
  for (int i = 0; i < 2; ++i) {
    int q = i * TPB + tid;  // 0..2047 float4 slots
    int r = q >> 6;
    int c4 = (q & 63) << 2;
    int idx = argi[r];
    const float4 ev = *(const float4*)&cw[(size_t)(1 + idx) * KD + c4];
    const float4 zv = *(const float4*)&z_s[r][c4];
    *(float4*)&out[ZQ_OFF + (size_t)(n0 + r) * KD + c4] = ev;
    float mk = mask_s[r];
    float dx = zv.x - ev.x, dy = zv.y - ev.y, dz2 = zv.z - ev.z,
          dw = zv.w - ev.w;
    csum += mk * (dx * dx + dy * dy + dz2 * dz2 + dw * dw);
    if (r > 0) {
      const float4 pv = *(const float4*)&z_s[r - 1][c4];
      float ax = zv.x - pv.x, ay = zv.y - pv.y, az = zv.z - pv.z,
            aw = zv.w - pv.w;
      ssum += mk * (ax * ax + ay * ay + az * az + aw * aw);
    } else if (has_prev) {
      const float4 pv = *(const float4*)&z[(size_t)(n0 - 1) * KD + c4];
      float ax = zv.x - pv.x, ay = zv.y - pv.y, az = zv.z - pv.z,
            aw = zv.w - pv.w;
      ssum += mk * (ax * ax + ay * ay + az * az + aw * aw);
    }
  }
#pragma unroll
  for (int d = 1; d <= 32; d <<= 1) {
    csum += __shfl_xor(csum, d);
    ssum += __shfl_xor(ssum, d);
  }
  if (lane == 0) { cred[w] = csum; sred[w] = ssum; }
  __syncthreads();
  if (tid == 0) {
    float cs = 0.f, ss2 = 0.f;
#pragma unroll
    for (int i = 0; i < 16; ++i) { cs += cred[i]; ss2 += sred[i]; }
    ws[WS_CSUM + blockIdx.x] = cs;
    ws[WS_SSUM + blockIdx.x] = ss2;
    float ms = 0.f;
    for (int r2 = 0; r2 < BM; ++r2) ms += mask_s[r2];
    ws[WS_MSUM + blockIdx.x] = ms;
  }
}

// ---------- fallback (fp32 path) if ws too small ----------
__global__ __launch_bounds__(256, 2) void tok_fb(
    const float* __restrict__ z, const float* __restrict__ mask,
    const float* __restrict__ cw, float* __restrict__ out,
    float* __restrict__ ws) {
  __shared__ __align__(16) float z_s[BM][KD];
  __shared__ int argi_s[BM];
  __shared__ float cred[4], sred[4];
  const int tid = threadIdx.x;
  const int lane = tid & 63;
  const int wave = tid >> 6;
  const int n0 = blockIdx.x * BM;
  const float* e = cw + KD;
#pragma unroll
  for (int i = 0; i < 8; ++i) {
    int seg = wave * 8 + i;
    gl_lds16(&z[(size_t)(n0 + seg) * KD + lane * 4], &z_s[seg][0]);
  }
  __syncthreads();
  float acc[8][16];
#pragma unroll
  for (int r = 0; r < 8; ++r)
#pragma unroll
    for (int m = 0; m < 16; ++m) acc[r][m] = 0.f;
#pragma unroll 1
  for (int i = 0; i < 64; ++i) {
    float4 ef[16];
#pragma unroll
    for (int m = 0; m < 16; ++m)
      ef[m] = *(const float4*)&e[(size_t)((m << 6) + lane) * KD + (i << 2)];
    float4 zf[8];
#pragma unroll
    for (int rr = 0; rr < 8; ++rr)
      zf[rr] = *(const float4*)&z_s[(wave << 3) + rr][i << 2];
#pragma unroll
    for (int m = 0; m < 16; ++m)
#pragma unroll
      for (int rr = 0; rr < 8; ++rr)
        acc[rr][m] += zf[rr].x * ef[m].x + zf[rr].y * ef[m].y +
                      zf[rr].z * ef[m].z + zf[rr].w * ef[m].w;
  }
  const int rowbase = wave << 3;
#pragma unroll
  for (int rr = 0; rr < 8; ++rr) {
    float mv = acc[rr][0];
    int mc = lane;
#pragma unroll
    for (int m = 1; m < 16; ++m) {
      float v = acc[rr][m];
      int c = (m << 6) + lane;
      bool tk = v > mv;
      mc = tk ? c : mc;
      mv = tk ? v : mv;
    }
#pragma unroll
    for (int d = 32; d >= 1; d >>= 1) {
      float ov = __shfl_xor(mv, d);
      int oc = __shfl_xor(mc, d);
      bool tk = (ov > mv) || (ov == mv && oc < mc);
      mv = tk ? ov : mv;
      mc = tk ? oc : mc;
    }
    float sum = 0.f;
#pragma unroll
    for (int m = 0; m < 16; ++m) sum += __expf(acc[rr][m] - mv);
#pragma unroll
    for (int d = 32; d >= 1; d >>= 1) sum += __shfl_xor(sum, d);
    float lse = mv + __logf(sum);
    size_t base = LP_OFF + (size_t)(n0 + rowbase + rr) * VV;
#pragma unroll
    for (int m = 0; m < 16; ++m) out[base + (m << 6) + lane] = acc[rr][m] - lse;
    if (lane == 0) {
      argi_s[rowbase + rr] = mc;
      atomicAdd(&ws[WS_HIST + mc], mask[n0 + rowbase + rr]);
    }
  }
  __syncthreads();
  float csum = 0.f, ssum = 0.f;
  const bool has_prev = (n0 % TT) != 0;
#pragma unroll
  for (int i = 0; i < 8; ++i) {
    int q = i * 256 + tid;
    int r = q >> 6;
    int c4 = (q & 63) << 2;
    int idx = argi_s[r];
    const float4 ev = *(const float4*)&e[(size_t)idx * KD + c4];
    const float4 zv = *(const float4*)&z_s[r][c4];
    *(float4*)&out[ZQ_OFF + (size_t)(n0 + r) * KD + c4] = ev;
    float mk = mask[n0 + r];
    float dx = zv.x - ev.x, dy = zv.y - ev.y, dz2 = zv.z - ev.z, dw = zv.w - ev.w;
    csum += mk * (dx * dx + dy * dy + dz2 * dz2 + dw * dw);
    if (r > 0) {
      const float4 pv = *(const float4*)&z_s[r - 1][c4];
      float ax = zv.x - pv.x, ay = zv.y - pv.y, az = zv.z - pv.z, aw = zv.w - pv.w;
      ssum += mk * (ax * ax + ay * ay + az * az + aw * aw);
    } else if (has_prev) {
      const float4 pv = *(const float4*)&z[(size_t)(n0 - 1) * KD + c4];
      float ax = zv.x - pv.x, ay = zv.y - pv.y, az = zv.z - pv.z, aw = zv.w - pv.w;
      ssum += mk * (ax * ax + ay * ay + az * az + aw * aw);
    }
  }
#pragma unroll
  for (int d = 32; d >= 1; d >>= 1) {
    csum += __shfl_xor(csum, d);
    ssum += __shfl_xor(ssum, d);
  }
  if (lane == 0) { cred[wave] = csum; sred[wave] = ssum; }
  __syncthreads();
  if (tid == 0) {
    ws[WS_CSUM + blockIdx.x] = cred[0] + cred[1] + cred[2] + cred[3];
    ws[WS_SSUM + blockIdx.x] = sred[0] + sred[1] + sred[2] + sred[3];
    float ms = 0.f;
    for (int r2 = 0; r2 < BM; ++r2) ms += mask[n0 + r2];
    ws[WS_MSUM + blockIdx.x] = ms;
  }
}

__global__ __launch_bounds__(1024) void tok_final(const float* __restrict__ ws,
                                                  float* __restrict__ out) {
  const int t = threadIdx.x;
  const int lane = t & 63, w = t >> 6;
  __shared__ float red[16];
  auto blockReduce = [&](float v) -> float {
#pragma unroll
    for (int d = 32; d >= 1; d >>= 1) v += __shfl_xor(v, d);
    __syncthreads();
    if (lane == 0) red[w] = v;
    __syncthreads();
    float s = 0.f;
#pragma unroll
    for (int i = 0; i < 16; ++i) s += red[i];
    return s;
  };
  float Mtot = blockReduce(ws[WS_MSUM + t]);
  float Ctot = blockReduce(ws[WS_CSUM + t]);
  float Stot = blockReduce(ws[WS_SSUM + t]);
  float prob = ws[WS_HIST + t] / Mtot;
  float psum = blockReduce(prob);
  out[EM_OFF + t] = prob / psum;
  if (t == 0) {
    float vc = Mtot * (float)KD;
    out[0] = Stot / vc;  // smoothness_loss
    out[1] = Ctot / vc;  // commitment_loss
  }
}

extern "C" void kernel_launch(void* const* d_in, const int* in_sizes, int n_in,
                              void* d_out, int out_size, void* d_ws,
                              size_t ws_size, hipStream_t stream) {
  const float* z = (const float*)d_in[0];
  const float* mask = (const float*)d_in[1];
  const float* cw = (const float*)d_in[2];
  float* out = (float*)d_out;
  float* ws = (float*)d_ws;
  hipMemsetAsync(ws, 0, 1024 * sizeof(float), stream);  // histogram zeros
  if (ws_size >= (size_t)WS_NEED) {
    unsigned short* e8 = (unsigned short*)(ws + WS_E8);
    tok_prep<<<128, 256, 0, stream>>>(cw, e8);
    tok_mfma<<<NBLK, TPB, 0, stream>>>(z, mask, cw, e8, out, ws);
  } else {
    tok_fb<<<NBLK, 256, 0, stream>>>(z, mask, cw, out, ws);
  }
  tok_final<<<1, 1024, 0, stream>>>(ws, out);
}